// Round 1
// baseline (1035.425 us; speedup 1.0000x reference)
//
#include <hip/hip_runtime.h>
#include <hip/hip_bf16.h>
#include <math.h>

// Problem constants (CompactPointMamba: B=4, N=2048, E=128)
#define BATCH 4
#define NPTS  2048
#define L     4096      // 2*NPTS after concat of hilbert/trans orders
#define E     128
#define DI    256       // E*EXP
#define DS    16
#define DRR   8         // (E+15)//16
#define DCV   4
#define NBLK  2
#define NC    40
#define XDW   40        // DR + 2*DS
#define ROWS  (BATCH*L) // 16384
#define CH    64        // scan chunk length
#define NCH   64        // L / CH

// ---------------------------------------------------------------- embed
__global__ void embed_kernel(const float* __restrict__ x,
                             const int* __restrict__ oh, const int* __restrict__ ot,
                             const float* __restrict__ pe_w, const float* __restrict__ pe_b,
                             const float* __restrict__ gamma, const float* __restrict__ beta,
                             float* __restrict__ h) {
  int idx = blockIdx.x * 256 + threadIdx.x;    // over ROWS*E
  if (idx >= ROWS * E) return;
  int e = idx % E;
  int r = idx / E;       // b*L + n
  int n = r % L;
  int b = r / L;
  int g = (n >= NPTS) ? 1 : 0;
  int nn = n - g * NPTS;
  int src = g ? ot[b * NPTS + nn] : oh[b * NPTS + nn];
  const float* xp = x + ((size_t)b * NPTS + src) * 3;
  float v = pe_b[e] + xp[0] * pe_w[e * 3 + 0] + xp[1] * pe_w[e * 3 + 1] + xp[2] * pe_w[e * 3 + 2];
  h[idx] = v * gamma[g * E + e] + beta[g * E + e];
}

// ---------------------------------------------------------------- layernorm (wave per row)
__global__ void ln_kernel(const float* __restrict__ src, float* __restrict__ dst,
                          const float* __restrict__ g, const float* __restrict__ bb, int rows) {
  int wave = threadIdx.x >> 6;
  int lane = threadIdx.x & 63;
  int row = blockIdx.x * 4 + wave;
  if (row >= rows) return;
  const float* p = src + (size_t)row * E;
  float x0 = p[lane], x1 = p[lane + 64];
  float s1 = x0 + x1, s2 = x0 * x0 + x1 * x1;
  #pragma unroll
  for (int off = 32; off > 0; off >>= 1) {
    s1 += __shfl_xor(s1, off);
    s2 += __shfl_xor(s2, off);
  }
  float m = s1 * (1.0f / E);
  float v = s2 * (1.0f / E) - m * m;
  float inv = rsqrtf(v + 1e-5f);
  float* q = dst + (size_t)row * E;
  q[lane]      = (x0 - m) * inv * g[lane]      + bb[lane];
  q[lane + 64] = (x1 - m) * inv * g[lane + 64] + bb[lane + 64];
}

// ---------------------------------------------------------------- generic fp32 GEMM  C = act(A @ B^T + bias) [+C]
// A: (M,K) lda   B: (N,K) ldb   C: (M,N) ldc
// ACT: 0 = none, 1 = softplus.  ACC: 1 = C += result.
template<int ACT, int ACC>
__global__ void gemm_bt(const float* __restrict__ A, int lda,
                        const float* __restrict__ B, int ldb,
                        const float* __restrict__ bias,
                        float* __restrict__ C, int ldc,
                        int M, int N, int K) {
  __shared__ float As[64][17];
  __shared__ float Bs[64][17];
  int tx = threadIdx.x % 16, ty = threadIdx.x / 16;
  int rowBase = blockIdx.x * 64, colBase = blockIdx.y * 64;
  float acc[4][4] = {};
  int lr = threadIdx.x / 4;        // 0..63
  int lc = (threadIdx.x % 4) * 4;  // 0,4,8,12
  for (int k0 = 0; k0 < K; k0 += 16) {
    #pragma unroll
    for (int j = 0; j < 4; j++) {
      int k = k0 + lc + j;
      int ar = rowBase + lr;
      As[lr][lc + j] = (ar < M && k < K) ? A[(size_t)ar * lda + k] : 0.f;
      int br = colBase + lr;
      Bs[lr][lc + j] = (br < N && k < K) ? B[(size_t)br * ldb + k] : 0.f;
    }
    __syncthreads();
    #pragma unroll
    for (int kk = 0; kk < 16; kk++) {
      float a[4], bv[4];
      #pragma unroll
      for (int i = 0; i < 4; i++) a[i] = As[ty * 4 + i][kk];
      #pragma unroll
      for (int j = 0; j < 4; j++) bv[j] = Bs[tx * 4 + j][kk];
      #pragma unroll
      for (int i = 0; i < 4; i++)
        #pragma unroll
        for (int j = 0; j < 4; j++) acc[i][j] += a[i] * bv[j];
    }
    __syncthreads();
  }
  #pragma unroll
  for (int i = 0; i < 4; i++) {
    int r = rowBase + ty * 4 + i;
    if (r >= M) continue;
    #pragma unroll
    for (int j = 0; j < 4; j++) {
      int c = colBase + tx * 4 + j;
      if (c >= N) continue;
      float v = acc[i][j];
      if (bias) v += bias[c];
      if (ACT == 1) v = (v > 20.f) ? v : log1pf(expf(v));  // softplus
      if (ACC) C[(size_t)r * ldc + c] += v;
      else     C[(size_t)r * ldc + c] = v;
    }
  }
}

// ---------------------------------------------------------------- causal depthwise conv (DC=4) + silu
__global__ void conv_silu(const float* __restrict__ u, const float* __restrict__ cw,
                          const float* __restrict__ cb, float* __restrict__ uc) {
  int idx = blockIdx.x * 256 + threadIdx.x;    // over ROWS*DI
  if (idx >= ROWS * DI) return;
  int d = idx % DI;
  int r = idx / DI;     // b*L + t
  int t = r % L;
  int b = r / L;
  float acc = cb[d];
  #pragma unroll
  for (int k = 0; k < DCV; k++) {
    int tt = t + k - (DCV - 1);
    if (tt >= 0) acc += u[((size_t)b * L + tt) * DI + d] * cw[d * DCV + k];
  }
  uc[idx] = acc / (1.f + expf(-acc));   // silu
}

// ---------------------------------------------------------------- selective scan, pass A: chunk-local from zero init
// grid: BATCH*NCH blocks x 256 threads (thread = d)
__global__ void scan_passA(const float* __restrict__ delta, const float* __restrict__ uc,
                           const float* __restrict__ xdbl, const float* __restrict__ A_log,
                           float* __restrict__ hloc, float* __restrict__ sumd) {
  int b = blockIdx.x / NCH, c = blockIdx.x % NCH;
  int d = threadIdx.x;
  __shared__ float Bsh[CH][DS];
  for (int i = threadIdx.x; i < CH * DS; i += 256) {
    int t0 = i / DS, s = i % DS;
    Bsh[t0][s] = xdbl[((size_t)b * L + c * CH + t0) * XDW + DRR + s];
  }
  __syncthreads();
  float Av[DS];
  #pragma unroll
  for (int s = 0; s < DS; s++) Av[s] = -expf(A_log[d * DS + s]);
  float st[DS] = {};
  float sd = 0.f;
  const float* dl_p = delta + ((size_t)b * L + c * CH) * DI + d;
  const float* uc_p = uc    + ((size_t)b * L + c * CH) * DI + d;
  for (int t0 = 0; t0 < CH; t0++) {
    float dl = dl_p[(size_t)t0 * DI];
    float ut = uc_p[(size_t)t0 * DI];
    sd += dl;
    float du = dl * ut;
    #pragma unroll
    for (int s = 0; s < DS; s++) {
      float a = expf(dl * Av[s]);
      st[s] = a * st[s] + du * Bsh[t0][s];
    }
  }
  size_t chain = (size_t)b * DI + d;
  #pragma unroll
  for (int s = 0; s < DS; s++) hloc[(chain * NCH + c) * DS + s] = st[s];
  sumd[chain * NCH + c] = sd;
}

// ---------------------------------------------------------------- scan pass B: sequential combine over chunks
__global__ void scan_passB(const float* __restrict__ A_log, const float* __restrict__ hloc,
                           const float* __restrict__ sumd, float* __restrict__ hinit) {
  int chain = blockIdx.x * 256 + threadIdx.x;   // b*DI + d
  if (chain >= BATCH * DI) return;
  int d = chain % DI;
  float Av[DS];
  #pragma unroll
  for (int s = 0; s < DS; s++) Av[s] = -expf(A_log[d * DS + s]);
  float hst[DS] = {};
  for (int c = 0; c < NCH; c++) {
    size_t base = ((size_t)chain * NCH + c) * DS;
    #pragma unroll
    for (int s = 0; s < DS; s++) hinit[base + s] = hst[s];
    float sd = sumd[(size_t)chain * NCH + c];
    #pragma unroll
    for (int s = 0; s < DS; s++) hst[s] = expf(Av[s] * sd) * hst[s] + hloc[base + s];
  }
}

// ---------------------------------------------------------------- scan pass C: re-run with true init, y = scan_y * silu(z)
__global__ void scan_passC(const float* __restrict__ delta, const float* __restrict__ uc,
                           const float* __restrict__ xdbl, const float* __restrict__ A_log,
                           const float* __restrict__ Dp, const float* __restrict__ z,
                           const float* __restrict__ hinit, float* __restrict__ y) {
  int b = blockIdx.x / NCH, c = blockIdx.x % NCH;
  int d = threadIdx.x;
  __shared__ float Bsh[CH][DS];
  __shared__ float Csh[CH][DS];
  for (int i = threadIdx.x; i < CH * DS; i += 256) {
    int t0 = i / DS, s = i % DS;
    size_t rb = ((size_t)b * L + c * CH + t0) * XDW;
    Bsh[t0][s] = xdbl[rb + DRR + s];
    Csh[t0][s] = xdbl[rb + DRR + DS + s];
  }
  __syncthreads();
  float Av[DS];
  #pragma unroll
  for (int s = 0; s < DS; s++) Av[s] = -expf(A_log[d * DS + s]);
  size_t chain = (size_t)b * DI + d;
  float st[DS];
  #pragma unroll
  for (int s = 0; s < DS; s++) st[s] = hinit[(chain * NCH + c) * DS + s];
  float Dv = Dp[d];
  const float* dl_p = delta + ((size_t)b * L + c * CH) * DI + d;
  const float* uc_p = uc    + ((size_t)b * L + c * CH) * DI + d;
  const float* z_p  = z     + ((size_t)b * L + c * CH) * DI + d;
  float* y_p        = y     + ((size_t)b * L + c * CH) * DI + d;
  for (int t0 = 0; t0 < CH; t0++) {
    float dl = dl_p[(size_t)t0 * DI];
    float ut = uc_p[(size_t)t0 * DI];
    float du = dl * ut;
    float acc = Dv * ut;
    #pragma unroll
    for (int s = 0; s < DS; s++) {
      float a = expf(dl * Av[s]);
      st[s] = a * st[s] + du * Bsh[t0][s];
      acc += st[s] * Csh[t0][s];
    }
    float zz = z_p[(size_t)t0 * DI];
    float sz = zz / (1.f + expf(-zz));
    y_p[(size_t)t0 * DI] = acc * sz;
  }
}

// ---------------------------------------------------------------- final mean helpers
__global__ void zero_kernel(float* __restrict__ p, int n) {
  int i = blockIdx.x * 256 + threadIdx.x;
  if (i < n) p[i] = 0.f;
}

// grid: BATCH*64 blocks x 128 threads; each block sums 64 rows of one batch
__global__ void colsum_kernel(const float* __restrict__ xn, float* __restrict__ hm) {
  int b = blockIdx.x / 64;
  int r0 = (blockIdx.x % 64) * 64;
  int e = threadIdx.x;
  float acc = 0.f;
  for (int r = 0; r < 64; r++) acc += xn[((size_t)b * L + r0 + r) * E + e];
  atomicAdd(&hm[b * E + e], acc);
}

__global__ void fc_kernel(const float* __restrict__ hm, const float* __restrict__ fcw,
                          const float* __restrict__ fcb, float* __restrict__ out) {
  int i = threadIdx.x;
  if (i >= BATCH * NC) return;
  int b = i / NC, o = i % NC;
  float acc = 0.f;
  for (int e = 0; e < E; e++) acc += hm[b * E + e] * fcw[o * E + e];
  out[i] = acc * (1.f / L) + fcb[o];
}

// ---------------------------------------------------------------- launch
extern "C" void kernel_launch(void* const* d_in, const int* in_sizes, int n_in,
                              void* d_out, int out_size, void* d_ws, size_t ws_size,
                              hipStream_t stream) {
  const float* x      = (const float*)d_in[0];
  const int*   oh     = (const int*)d_in[1];
  const int*   ot     = (const int*)d_in[2];
  const float* pe_w   = (const float*)d_in[3];
  const float* pe_b   = (const float*)d_in[4];
  const float* gamma  = (const float*)d_in[5];
  const float* beta   = (const float*)d_in[6];
  const float* ln_g   = (const float*)d_in[7];
  const float* ln_b   = (const float*)d_in[8];
  const float* inproj = (const float*)d_in[9];
  const float* conv_w = (const float*)d_in[10];
  const float* conv_b = (const float*)d_in[11];
  const float* xproj  = (const float*)d_in[12];
  const float* dtw    = (const float*)d_in[13];
  const float* dtb    = (const float*)d_in[14];
  const float* A_log  = (const float*)d_in[15];
  const float* Dp     = (const float*)d_in[16];
  const float* outw   = (const float*)d_in[17];
  const float* hn_g   = (const float*)d_in[18];
  const float* hn_b   = (const float*)d_in[19];
  const float* fc_w   = (const float*)d_in[20];
  const float* fc_b   = (const float*)d_in[21];
  float* out = (float*)d_out;

  char* ws = (char*)d_ws;
  size_t off = 0;
  auto alloc = [&](size_t bytes) { size_t o = off; off += (bytes + 255) & ~(size_t)255; return o; };
  float* h     = (float*)(ws + alloc((size_t)ROWS * E * 4));            // 8 MB
  float* xn    = (float*)(ws + alloc((size_t)ROWS * E * 4));            // 8 MB
  float* u     = (float*)(ws + alloc((size_t)ROWS * DI * 4));           // 16 MB (reused as y)
  float* z     = (float*)(ws + alloc((size_t)ROWS * DI * 4));           // 16 MB
  float* uc    = (float*)(ws + alloc((size_t)ROWS * DI * 4));           // 16 MB
  float* xdbl  = (float*)(ws + alloc((size_t)ROWS * XDW * 4));          // 2.6 MB
  float* delta = (float*)(ws + alloc((size_t)ROWS * DI * 4));           // 16 MB
  float* hloc  = (float*)(ws + alloc((size_t)BATCH * DI * NCH * DS * 4)); // 4 MB
  float* sumd  = (float*)(ws + alloc((size_t)BATCH * DI * NCH * 4));    // 256 KB
  float* hinit = (float*)(ws + alloc((size_t)BATCH * DI * NCH * DS * 4)); // 4 MB
  float* hm    = (float*)(ws + alloc((size_t)BATCH * E * 4));           // 2 KB
  float* y     = u;   // u is dead after conv; reuse its buffer for y

  embed_kernel<<<(ROWS * E + 255) / 256, 256, 0, stream>>>(x, oh, ot, pe_w, pe_b, gamma, beta, h);

  for (int i = 0; i < NBLK; i++) {
    ln_kernel<<<ROWS / 4, 256, 0, stream>>>(h, xn, ln_g + i * E, ln_b + i * E, ROWS);

    dim3 g1(ROWS / 64, DI / 64);
    gemm_bt<0, 0><<<g1, 256, 0, stream>>>(xn, E, inproj + (size_t)i * 2 * DI * E, E,
                                          nullptr, u, DI, ROWS, DI, E);
    gemm_bt<0, 0><<<g1, 256, 0, stream>>>(xn, E, inproj + (size_t)i * 2 * DI * E + (size_t)DI * E, E,
                                          nullptr, z, DI, ROWS, DI, E);

    conv_silu<<<(ROWS * DI + 255) / 256, 256, 0, stream>>>(u, conv_w + i * DI * DCV, conv_b + i * DI, uc);

    dim3 g2(ROWS / 64, (XDW + 63) / 64);
    gemm_bt<0, 0><<<g2, 256, 0, stream>>>(uc, DI, xproj + (size_t)i * XDW * DI, DI,
                                          nullptr, xdbl, XDW, ROWS, XDW, DI);

    dim3 g3(ROWS / 64, DI / 64);
    gemm_bt<1, 0><<<g3, 256, 0, stream>>>(xdbl, XDW, dtw + (size_t)i * DI * DRR, DRR,
                                          dtb + i * DI, delta, DI, ROWS, DI, DRR);

    scan_passA<<<BATCH * NCH, 256, 0, stream>>>(delta, uc, xdbl, A_log + (size_t)i * DI * DS, hloc, sumd);
    scan_passB<<<(BATCH * DI + 255) / 256, 256, 0, stream>>>(A_log + (size_t)i * DI * DS, hloc, sumd, hinit);
    scan_passC<<<BATCH * NCH, 256, 0, stream>>>(delta, uc, xdbl, A_log + (size_t)i * DI * DS,
                                                Dp + i * DI, z, hinit, y);

    dim3 g4(ROWS / 64, E / 64);
    gemm_bt<0, 1><<<g4, 256, 0, stream>>>(y, DI, outw + (size_t)i * E * DI, DI,
                                          nullptr, h, E, ROWS, E, DI);
  }

  ln_kernel<<<ROWS / 4, 256, 0, stream>>>(h, xn, hn_g, hn_b, ROWS);
  zero_kernel<<<2, 256, 0, stream>>>(hm, BATCH * E);
  colsum_kernel<<<BATCH * 64, 128, 0, stream>>>(xn, hm);
  fc_kernel<<<1, 192, 0, stream>>>(hm, fc_w, fc_b, out);
}

// Round 3
// 857.761 us; speedup vs baseline: 1.2071x; 1.2071x over previous
//
#include <hip/hip_runtime.h>
#include <hip/hip_bf16.h>
#include <math.h>

// Problem constants (CompactPointMamba: B=4, N=2048, E=128)
#define BATCH 4
#define NPTS  2048
#define L     4096      // 2*NPTS after concat of hilbert/trans orders
#define E     128
#define DI    256       // E*EXP
#define DS    16
#define DRR   8         // (E+15)//16
#define DCV   4
#define NBLK  2
#define NC    40
#define XDW   40        // DR + 2*DS
#define ROWS  (BATCH*L) // 16384
#define CH    64        // scan chunk length
#define NCH   64        // L / CH

// ---------------------------------------------------------------- embed
__global__ void embed_kernel(const float* __restrict__ x,
                             const int* __restrict__ oh, const int* __restrict__ ot,
                             const float* __restrict__ pe_w, const float* __restrict__ pe_b,
                             const float* __restrict__ gamma, const float* __restrict__ beta,
                             float* __restrict__ h) {
  int idx = blockIdx.x * 256 + threadIdx.x;    // over ROWS*E
  if (idx >= ROWS * E) return;
  int e = idx % E;
  int r = idx / E;       // b*L + n
  int n = r % L;
  int b = r / L;
  int g = (n >= NPTS) ? 1 : 0;
  int nn = n - g * NPTS;
  int src = g ? ot[b * NPTS + nn] : oh[b * NPTS + nn];
  const float* xp = x + ((size_t)b * NPTS + src) * 3;
  float v = pe_b[e] + xp[0] * pe_w[e * 3 + 0] + xp[1] * pe_w[e * 3 + 1] + xp[2] * pe_w[e * 3 + 2];
  h[idx] = v * gamma[g * E + e] + beta[g * E + e];
}

// ---------------------------------------------------------------- layernorm (wave per row)
__global__ void ln_kernel(const float* __restrict__ src, float* __restrict__ dst,
                          const float* __restrict__ g, const float* __restrict__ bb, int rows) {
  int wave = threadIdx.x >> 6;
  int lane = threadIdx.x & 63;
  int row = blockIdx.x * 4 + wave;
  if (row >= rows) return;
  const float* p = src + (size_t)row * E;
  float x0 = p[lane], x1 = p[lane + 64];
  float s1 = x0 + x1, s2 = x0 * x0 + x1 * x1;
  #pragma unroll
  for (int off = 32; off > 0; off >>= 1) {
    s1 += __shfl_xor(s1, off);
    s2 += __shfl_xor(s2, off);
  }
  float m = s1 * (1.0f / E);
  float v = s2 * (1.0f / E) - m * m;
  float inv = rsqrtf(v + 1e-5f);
  float* q = dst + (size_t)row * E;
  q[lane]      = (x0 - m) * inv * g[lane]      + bb[lane];
  q[lane + 64] = (x1 - m) * inv * g[lane + 64] + bb[lane + 64];
}

// ---------------------------------------------------------------- generic fp32 GEMM  C = act(A @ B^T + bias) [+C]
// A: (M,K) lda   B: (N,K) ldb   C: (M,N) ldc
// ACT: 0 = none, 1 = softplus.  ACC: 1 = C += result.
template<int ACT, int ACC>
__global__ void gemm_bt(const float* __restrict__ A, int lda,
                        const float* __restrict__ B, int ldb,
                        const float* __restrict__ bias,
                        float* __restrict__ C, int ldc,
                        int M, int N, int K) {
  __shared__ float As[64][17];
  __shared__ float Bs[64][17];
  int tx = threadIdx.x % 16, ty = threadIdx.x / 16;
  int rowBase = blockIdx.x * 64, colBase = blockIdx.y * 64;
  float acc[4][4] = {};
  int lr = threadIdx.x / 4;        // 0..63
  int lc = (threadIdx.x % 4) * 4;  // 0,4,8,12
  for (int k0 = 0; k0 < K; k0 += 16) {
    #pragma unroll
    for (int j = 0; j < 4; j++) {
      int k = k0 + lc + j;
      int ar = rowBase + lr;
      As[lr][lc + j] = (ar < M && k < K) ? A[(size_t)ar * lda + k] : 0.f;
      int br = colBase + lr;
      Bs[lr][lc + j] = (br < N && k < K) ? B[(size_t)br * ldb + k] : 0.f;
    }
    __syncthreads();
    #pragma unroll
    for (int kk = 0; kk < 16; kk++) {
      float a[4], bv[4];
      #pragma unroll
      for (int i = 0; i < 4; i++) a[i] = As[ty * 4 + i][kk];
      #pragma unroll
      for (int j = 0; j < 4; j++) bv[j] = Bs[tx * 4 + j][kk];
      #pragma unroll
      for (int i = 0; i < 4; i++)
        #pragma unroll
        for (int j = 0; j < 4; j++) acc[i][j] += a[i] * bv[j];
    }
    __syncthreads();
  }
  #pragma unroll
  for (int i = 0; i < 4; i++) {
    int r = rowBase + ty * 4 + i;
    if (r >= M) continue;
    #pragma unroll
    for (int j = 0; j < 4; j++) {
      int c = colBase + tx * 4 + j;
      if (c >= N) continue;
      float v = acc[i][j];
      if (bias) v += bias[c];
      if (ACT == 1) v = (v > 20.f) ? v : log1pf(expf(v));  // softplus
      if (ACC) C[(size_t)r * ldc + c] += v;
      else     C[(size_t)r * ldc + c] = v;
    }
  }
}

// ---------------------------------------------------------------- causal depthwise conv (DC=4) + silu
// u lives in uz buffer: row stride 2*DI, columns 0..DI-1
__global__ void conv_silu(const float* __restrict__ uz, const float* __restrict__ cw,
                          const float* __restrict__ cb, float* __restrict__ uc) {
  int idx = blockIdx.x * 256 + threadIdx.x;    // over ROWS*DI
  if (idx >= ROWS * DI) return;
  int d = idx % DI;
  int r = idx / DI;     // b*L + t
  int t = r % L;
  int b = r / L;
  float acc = cb[d];
  #pragma unroll
  for (int k = 0; k < DCV; k++) {
    int tt = t + k - (DCV - 1);
    if (tt >= 0) acc += uz[((size_t)b * L + tt) * (2 * DI) + d] * cw[d * DCV + k];
  }
  uc[idx] = acc / (1.f + expf(-acc));   // silu
}

// ---------------------------------------------------------------- selective scan, pass A: chunk-local from zero init
// grid: BATCH*NCH blocks x 256 threads (thread = d)
__global__ void scan_passA(const float* __restrict__ delta, const float* __restrict__ uc,
                           const float* __restrict__ xdbl, const float* __restrict__ A_log,
                           float* __restrict__ hloc, float* __restrict__ sumd) {
  int b = blockIdx.x / NCH, c = blockIdx.x % NCH;
  int d = threadIdx.x;
  __shared__ float Bsh[CH][DS];
  for (int i = threadIdx.x; i < CH * DS; i += 256) {
    int t0 = i / DS, s = i % DS;
    Bsh[t0][s] = xdbl[((size_t)b * L + c * CH + t0) * XDW + DRR + s];
  }
  __syncthreads();
  float Av[DS];
  #pragma unroll
  for (int s = 0; s < DS; s++) Av[s] = -expf(A_log[d * DS + s]);
  float st[DS] = {};
  float sd = 0.f;
  const float* dl_p = delta + ((size_t)b * L + c * CH) * DI + d;
  const float* uc_p = uc    + ((size_t)b * L + c * CH) * DI + d;
  for (int t0 = 0; t0 < CH; t0++) {
    float dl = dl_p[(size_t)t0 * DI];
    float ut = uc_p[(size_t)t0 * DI];
    sd += dl;
    float du = dl * ut;
    #pragma unroll
    for (int s = 0; s < DS; s++) {
      float a = expf(dl * Av[s]);
      st[s] = a * st[s] + du * Bsh[t0][s];
    }
  }
  size_t chain = (size_t)b * DI + d;
  #pragma unroll
  for (int s = 0; s < DS; s++) hloc[(chain * NCH + c) * DS + s] = st[s];
  sumd[chain * NCH + c] = sd;
}

// ---------------------------------------------------------------- scan pass B: wave-parallel affine scan over chunks
// one 64-lane wave per (chain, s); lane = chunk index c.
// recurrence: x_{c+1} = a_c * x_c + b_c, x_0 = 0;  hinit[c] = x_c
// grid: BATCH*DI*DS waves / 4 per block = 4096 blocks x 256 threads
__global__ void scan_passB(const float* __restrict__ A_log, const float* __restrict__ hloc,
                           const float* __restrict__ sumd, float* __restrict__ hinit) {
  int wid = (blockIdx.x * 256 + threadIdx.x) >> 6;   // chain*DS + s
  int lane = threadIdx.x & 63;                        // chunk c
  int chain = wid / DS;                               // b*DI + d
  int s = wid % DS;
  int d = chain % DI;
  float Av = -expf(A_log[d * DS + s]);
  float a = expf(Av * sumd[(size_t)chain * NCH + lane]);
  float bvl = hloc[((size_t)chain * NCH + lane) * DS + s];
  // inclusive scan: lane c ends holding composition f_c∘...∘f_0 as (a, bvl)
  #pragma unroll
  for (int off = 1; off < 64; off <<= 1) {
    float pa  = __shfl_up(a, off);
    float pbv = __shfl_up(bvl, off);
    if (lane >= off) { bvl = a * pbv + bvl; a = a * pa; }
  }
  // exclusive prefix applied to x_0 = 0  →  just the b-part of incl[c-1]
  float hb = __shfl_up(bvl, 1);
  if (lane == 0) hb = 0.f;
  hinit[((size_t)chain * NCH + lane) * DS + s] = hb;
}

// ---------------------------------------------------------------- scan pass C: re-run with true init, y = scan_y * silu(z)
// z lives in uz buffer at column offset DI, row stride 2*DI.  y may alias delta
// (same-thread read-before-write per element).
__global__ void scan_passC(const float* __restrict__ delta, const float* __restrict__ uc,
                           const float* __restrict__ xdbl, const float* __restrict__ A_log,
                           const float* __restrict__ Dp, const float* __restrict__ uz,
                           const float* __restrict__ hinit, float* __restrict__ y) {
  int b = blockIdx.x / NCH, c = blockIdx.x % NCH;
  int d = threadIdx.x;
  __shared__ float Bsh[CH][DS];
  __shared__ float Csh[CH][DS];
  for (int i = threadIdx.x; i < CH * DS; i += 256) {
    int t0 = i / DS, s = i % DS;
    size_t rb = ((size_t)b * L + c * CH + t0) * XDW;
    Bsh[t0][s] = xdbl[rb + DRR + s];
    Csh[t0][s] = xdbl[rb + DRR + DS + s];
  }
  __syncthreads();
  float Av[DS];
  #pragma unroll
  for (int s = 0; s < DS; s++) Av[s] = -expf(A_log[d * DS + s]);
  size_t chain = (size_t)b * DI + d;
  float st[DS];
  #pragma unroll
  for (int s = 0; s < DS; s++) st[s] = hinit[(chain * NCH + c) * DS + s];
  float Dv = Dp[d];
  const float* dl_p = delta + ((size_t)b * L + c * CH) * DI + d;
  const float* uc_p = uc    + ((size_t)b * L + c * CH) * DI + d;
  const float* z_p  = uz    + ((size_t)b * L + c * CH) * (2 * DI) + DI + d;
  float* y_p        = y     + ((size_t)b * L + c * CH) * DI + d;
  for (int t0 = 0; t0 < CH; t0++) {
    float dl = dl_p[(size_t)t0 * DI];
    float ut = uc_p[(size_t)t0 * DI];
    float du = dl * ut;
    float acc = Dv * ut;
    #pragma unroll
    for (int s = 0; s < DS; s++) {
      float a = expf(dl * Av[s]);
      st[s] = a * st[s] + du * Bsh[t0][s];
      acc += st[s] * Csh[t0][s];
    }
    float zz = z_p[(size_t)t0 * (2 * DI)];
    float sz = zz / (1.f + expf(-zz));
    y_p[(size_t)t0 * DI] = acc * sz;
  }
}

// ---------------------------------------------------------------- final mean helpers
__global__ void zero_kernel(float* __restrict__ p, int n) {
  int i = blockIdx.x * 256 + threadIdx.x;
  if (i < n) p[i] = 0.f;
}

// grid: BATCH*64 blocks x 128 threads; each block sums 64 rows of one batch
__global__ void colsum_kernel(const float* __restrict__ xn, float* __restrict__ hm) {
  int b = blockIdx.x / 64;
  int r0 = (blockIdx.x % 64) * 64;
  int e = threadIdx.x;
  float acc = 0.f;
  for (int r = 0; r < 64; r++) acc += xn[((size_t)b * L + r0 + r) * E + e];
  atomicAdd(&hm[b * E + e], acc);
}

__global__ void fc_kernel(const float* __restrict__ hm, const float* __restrict__ fcw,
                          const float* __restrict__ fcb, float* __restrict__ out) {
  int i = threadIdx.x;
  if (i >= BATCH * NC) return;
  int b = i / NC, o = i % NC;
  float acc = 0.f;
  for (int e = 0; e < E; e++) acc += hm[b * E + e] * fcw[o * E + e];
  out[i] = acc * (1.f / L) + fcb[o];
}

// ---------------------------------------------------------------- launch
extern "C" void kernel_launch(void* const* d_in, const int* in_sizes, int n_in,
                              void* d_out, int out_size, void* d_ws, size_t ws_size,
                              hipStream_t stream) {
  const float* x      = (const float*)d_in[0];
  const int*   oh     = (const int*)d_in[1];
  const int*   ot     = (const int*)d_in[2];
  const float* pe_w   = (const float*)d_in[3];
  const float* pe_b   = (const float*)d_in[4];
  const float* gamma  = (const float*)d_in[5];
  const float* beta   = (const float*)d_in[6];
  const float* ln_g   = (const float*)d_in[7];
  const float* ln_b   = (const float*)d_in[8];
  const float* inproj = (const float*)d_in[9];
  const float* conv_w = (const float*)d_in[10];
  const float* conv_b = (const float*)d_in[11];
  const float* xproj  = (const float*)d_in[12];
  const float* dtw    = (const float*)d_in[13];
  const float* dtb    = (const float*)d_in[14];
  const float* A_log  = (const float*)d_in[15];
  const float* Dp     = (const float*)d_in[16];
  const float* outw   = (const float*)d_in[17];
  const float* hn_g   = (const float*)d_in[18];
  const float* hn_b   = (const float*)d_in[19];
  const float* fc_w   = (const float*)d_in[20];
  const float* fc_b   = (const float*)d_in[21];
  float* out = (float*)d_out;

  char* ws = (char*)d_ws;
  size_t off = 0;
  auto alloc = [&](size_t bytes) { size_t o = off; off += (bytes + 255) & ~(size_t)255; return o; };
  float* h     = (float*)(ws + alloc((size_t)ROWS * E * 4));              // 8 MB
  float* xn    = (float*)(ws + alloc((size_t)ROWS * E * 4));              // 8 MB
  float* uz    = (float*)(ws + alloc((size_t)ROWS * 2 * DI * 4));         // 32 MB
  float* uc    = (float*)(ws + alloc((size_t)ROWS * DI * 4));             // 16 MB
  float* xdbl  = (float*)(ws + alloc((size_t)ROWS * XDW * 4));            // 2.6 MB
  float* delta = (float*)(ws + alloc((size_t)ROWS * DI * 4));             // 16 MB
  float* hloc  = (float*)(ws + alloc((size_t)BATCH * DI * NCH * DS * 4)); // 4 MB
  float* sumd  = (float*)(ws + alloc((size_t)BATCH * DI * NCH * 4));      // 256 KB
  float* hinit = (float*)(ws + alloc((size_t)BATCH * DI * NCH * DS * 4)); // 4 MB
  float* hm    = (float*)(ws + alloc((size_t)BATCH * E * 4));             // 2 KB
  float* y     = delta;   // passC: same-thread read-before-write per element

  embed_kernel<<<(ROWS * E + 255) / 256, 256, 0, stream>>>(x, oh, ot, pe_w, pe_b, gamma, beta, h);

  for (int i = 0; i < NBLK; i++) {
    ln_kernel<<<ROWS / 4, 256, 0, stream>>>(h, xn, ln_g + i * E, ln_b + i * E, ROWS);

    // fused u|z projection: (ROWS, 2*DI) = xn @ inproj^T
    dim3 g1(ROWS / 64, (2 * DI) / 64);
    gemm_bt<0, 0><<<g1, 256, 0, stream>>>(xn, E, inproj + (size_t)i * 2 * DI * E, E,
                                          nullptr, uz, 2 * DI, ROWS, 2 * DI, E);

    conv_silu<<<(ROWS * DI + 255) / 256, 256, 0, stream>>>(uz, conv_w + i * DI * DCV, conv_b + i * DI, uc);

    dim3 g2(ROWS / 64, (XDW + 63) / 64);
    gemm_bt<0, 0><<<g2, 256, 0, stream>>>(uc, DI, xproj + (size_t)i * XDW * DI, DI,
                                          nullptr, xdbl, XDW, ROWS, XDW, DI);

    dim3 g3(ROWS / 64, DI / 64);
    gemm_bt<1, 0><<<g3, 256, 0, stream>>>(xdbl, XDW, dtw + (size_t)i * DI * DRR, DRR,
                                          dtb + i * DI, delta, DI, ROWS, DI, DRR);

    scan_passA<<<BATCH * NCH, 256, 0, stream>>>(delta, uc, xdbl, A_log + (size_t)i * DI * DS, hloc, sumd);
    scan_passB<<<(BATCH * DI * DS) / 4, 256, 0, stream>>>(A_log + (size_t)i * DI * DS, hloc, sumd, hinit);
    scan_passC<<<BATCH * NCH, 256, 0, stream>>>(delta, uc, xdbl, A_log + (size_t)i * DI * DS,
                                                Dp + i * DI, uz, hinit, y);

    dim3 g4(ROWS / 64, E / 64);
    gemm_bt<0, 1><<<g4, 256, 0, stream>>>(y, DI, outw + (size_t)i * E * DI, DI,
                                          nullptr, h, E, ROWS, E, DI);
  }

  ln_kernel<<<ROWS / 4, 256, 0, stream>>>(h, xn, hn_g, hn_b, ROWS);
  zero_kernel<<<2, 256, 0, stream>>>(hm, BATCH * E);
  colsum_kernel<<<BATCH * 64, 128, 0, stream>>>(xn, hm);
  fc_kernel<<<1, 192, 0, stream>>>(hm, fc_w, fc_b, out);
}

// Round 4
// 522.329 us; speedup vs baseline: 1.9823x; 1.6422x over previous
//
#include <hip/hip_runtime.h>
#include <hip/hip_bf16.h>
#include <math.h>

// Problem constants (CompactPointMamba: B=4, N=2048, E=128)
#define BATCH 4
#define NPTS  2048
#define L     4096      // 2*NPTS after concat of hilbert/trans orders
#define E     128
#define DI    256       // E*EXP
#define DS    16
#define DRR   8         // (E+15)//16
#define DCV   4
#define NBLK  2
#define NC    40
#define XDW   40        // DR + 2*DS
#define ROWS  (BATCH*L) // 16384
#define CH    16        // scan chunk length
#define NCH   256       // L / CH

// ---------------------------------------------------------------- embed
__global__ void embed_kernel(const float* __restrict__ x,
                             const int* __restrict__ oh, const int* __restrict__ ot,
                             const float* __restrict__ pe_w, const float* __restrict__ pe_b,
                             const float* __restrict__ gamma, const float* __restrict__ beta,
                             float* __restrict__ h) {
  int idx = blockIdx.x * 256 + threadIdx.x;    // over ROWS*E
  if (idx >= ROWS * E) return;
  int e = idx % E;
  int r = idx / E;       // b*L + n
  int n = r % L;
  int b = r / L;
  int g = (n >= NPTS) ? 1 : 0;
  int nn = n - g * NPTS;
  int src = g ? ot[b * NPTS + nn] : oh[b * NPTS + nn];
  const float* xp = x + ((size_t)b * NPTS + src) * 3;
  float v = pe_b[e] + xp[0] * pe_w[e * 3 + 0] + xp[1] * pe_w[e * 3 + 1] + xp[2] * pe_w[e * 3 + 2];
  h[idx] = v * gamma[g * E + e] + beta[g * E + e];
}

// ---------------------------------------------------------------- layernorm (wave per row)
__global__ void ln_kernel(const float* __restrict__ src, float* __restrict__ dst,
                          const float* __restrict__ g, const float* __restrict__ bb, int rows) {
  int wave = threadIdx.x >> 6;
  int lane = threadIdx.x & 63;
  int row = blockIdx.x * 4 + wave;
  if (row >= rows) return;
  const float* p = src + (size_t)row * E;
  float x0 = p[lane], x1 = p[lane + 64];
  float s1 = x0 + x1, s2 = x0 * x0 + x1 * x1;
  #pragma unroll
  for (int off = 32; off > 0; off >>= 1) {
    s1 += __shfl_xor(s1, off);
    s2 += __shfl_xor(s2, off);
  }
  float m = s1 * (1.0f / E);
  float v = s2 * (1.0f / E) - m * m;
  float inv = rsqrtf(v + 1e-5f);
  float* q = dst + (size_t)row * E;
  q[lane]      = (x0 - m) * inv * g[lane]      + bb[lane];
  q[lane + 64] = (x1 - m) * inv * g[lane + 64] + bb[lane + 64];
}

// ---------------------------------------------------------------- generic fp32 GEMM  C = act(A @ B^T + bias) [+C]
// A: (M,K) lda   B: (N,K) ldb   C: (M,N) ldc
// ACT: 0 = none, 1 = softplus.  ACC: 1 = C += result.
// LDS tiles are k-major (As[k][row]) so fragment reads are ds_read_b128.
template<int ACT, int ACC>
__global__ void gemm_bt(const float* __restrict__ A, int lda,
                        const float* __restrict__ B, int ldb,
                        const float* __restrict__ bias,
                        float* __restrict__ C, int ldc,
                        int M, int N, int K) {
  __shared__ float As[16][68];
  __shared__ float Bs[16][68];
  int tx = threadIdx.x % 16, ty = threadIdx.x / 16;
  int rowBase = blockIdx.x * 64, colBase = blockIdx.y * 64;
  float acc[4][4] = {};
  int lr = threadIdx.x / 4;        // 0..63
  int lc = (threadIdx.x % 4) * 4;  // 0,4,8,12
  for (int k0 = 0; k0 < K; k0 += 16) {
    int ar = rowBase + lr;           // M is a multiple of 64 -> always < M
    if (k0 + lc + 3 < K) {
      float4 v = *(const float4*)&A[(size_t)ar * lda + k0 + lc];
      As[lc + 0][lr] = v.x; As[lc + 1][lr] = v.y;
      As[lc + 2][lr] = v.z; As[lc + 3][lr] = v.w;
    } else {
      #pragma unroll
      for (int j = 0; j < 4; j++) {
        int k = k0 + lc + j;
        As[lc + j][lr] = (k < K) ? A[(size_t)ar * lda + k] : 0.f;
      }
    }
    int br = colBase + lr;
    if (br < N && k0 + lc + 3 < K) {
      float4 v = *(const float4*)&B[(size_t)br * ldb + k0 + lc];
      Bs[lc + 0][lr] = v.x; Bs[lc + 1][lr] = v.y;
      Bs[lc + 2][lr] = v.z; Bs[lc + 3][lr] = v.w;
    } else {
      #pragma unroll
      for (int j = 0; j < 4; j++) {
        int k = k0 + lc + j;
        Bs[lc + j][lr] = (br < N && k < K) ? B[(size_t)br * ldb + k] : 0.f;
      }
    }
    __syncthreads();
    #pragma unroll
    for (int kk = 0; kk < 16; kk++) {
      float4 a4 = *(const float4*)&As[kk][ty * 4];
      float4 b4 = *(const float4*)&Bs[kk][tx * 4];
      float a[4] = {a4.x, a4.y, a4.z, a4.w};
      float bv[4] = {b4.x, b4.y, b4.z, b4.w};
      #pragma unroll
      for (int i = 0; i < 4; i++)
        #pragma unroll
        for (int j = 0; j < 4; j++) acc[i][j] += a[i] * bv[j];
    }
    __syncthreads();
  }
  #pragma unroll
  for (int i = 0; i < 4; i++) {
    int r = rowBase + ty * 4 + i;
    if (r >= M) continue;
    #pragma unroll
    for (int j = 0; j < 4; j++) {
      int c = colBase + tx * 4 + j;
      if (c >= N) continue;
      float v = acc[i][j];
      if (bias) v += bias[c];
      if (ACT == 1) v = (v > 20.f) ? v : log1pf(expf(v));  // softplus
      if (ACC) C[(size_t)r * ldc + c] += v;
      else     C[(size_t)r * ldc + c] = v;
    }
  }
}

// ---------------------------------------------------------------- causal depthwise conv (DC=4) + silu
// u lives in uz buffer: row stride 2*DI, columns 0..DI-1
__global__ void conv_silu(const float* __restrict__ uz, const float* __restrict__ cw,
                          const float* __restrict__ cb, float* __restrict__ uc) {
  int idx = blockIdx.x * 256 + threadIdx.x;    // over ROWS*DI
  if (idx >= ROWS * DI) return;
  int d = idx % DI;
  int r = idx / DI;     // b*L + t
  int t = r % L;
  int b = r / L;
  float acc = cb[d];
  #pragma unroll
  for (int k = 0; k < DCV; k++) {
    int tt = t + k - (DCV - 1);
    if (tt >= 0) acc += uz[((size_t)b * L + tt) * (2 * DI) + d] * cw[d * DCV + k];
  }
  uc[idx] = acc / (1.f + __expf(-acc));   // silu
}

// ---------------------------------------------------------------- selective scan, pass A: chunk-local from zero init
// grid: BATCH*NCH blocks x 256 threads (thread = d)
__global__ void scan_passA(const float* __restrict__ delta, const float* __restrict__ uc,
                           const float* __restrict__ xdbl, const float* __restrict__ A_log,
                           float* __restrict__ hloc, float* __restrict__ sumd) {
  int b = blockIdx.x / NCH, c = blockIdx.x % NCH;
  int d = threadIdx.x;
  __shared__ float Bsh[CH][DS];
  {
    int i = threadIdx.x;   // CH*DS == 256 exactly
    int t0 = i / DS, s = i % DS;
    Bsh[t0][s] = xdbl[((size_t)b * L + c * CH + t0) * XDW + DRR + s];
  }
  __syncthreads();
  float Av[DS];
  #pragma unroll
  for (int s = 0; s < DS; s++) Av[s] = -__expf(A_log[d * DS + s]);
  float st[DS] = {};
  float sd = 0.f;
  const float* dl_p = delta + ((size_t)b * L + c * CH) * DI + d;
  const float* uc_p = uc    + ((size_t)b * L + c * CH) * DI + d;
  for (int t0 = 0; t0 < CH; t0++) {
    float dl = dl_p[(size_t)t0 * DI];
    float ut = uc_p[(size_t)t0 * DI];
    sd += dl;
    float du = dl * ut;
    #pragma unroll
    for (int s = 0; s < DS; s++) {
      float a = __expf(dl * Av[s]);
      st[s] = a * st[s] + du * Bsh[t0][s];
    }
  }
  size_t chain = (size_t)b * DI + d;
  #pragma unroll
  for (int s = 0; s < DS; s++) hloc[(chain * NCH + c) * DS + s] = st[s];
  sumd[chain * NCH + c] = sd;
}

// ---------------------------------------------------------------- scan pass B: wave-parallel affine scan over 256 chunks
// one 64-lane wave per (chain, s); each lane serially composes 4 adjacent
// chunks, wave-scan over lane composites, then replay 4 chunks locally.
// hinit may alias hloc: each (chain,c,s) element is read then written by the
// SAME thread (read in phase 1, write in phase 3), addresses disjoint across
// threads.
__global__ void scan_passB(const float* __restrict__ A_log, const float* __restrict__ hloc,
                           const float* __restrict__ sumd, float* __restrict__ hinit) {
  int wid = (blockIdx.x * 256 + threadIdx.x) >> 6;   // chain*DS + s
  int lane = threadIdx.x & 63;
  int chain = wid / DS;                               // b*DI + d
  int s = wid % DS;
  int d = chain % DI;
  float Av = -__expf(A_log[d * DS + s]);
  float aj[4], bj[4];
  float a = 1.f, bvl = 0.f;
  #pragma unroll
  for (int j = 0; j < 4; j++) {
    int c = lane * 4 + j;
    aj[j] = __expf(Av * sumd[(size_t)chain * NCH + c]);
    bj[j] = hloc[((size_t)chain * NCH + c) * DS + s];
    bvl = aj[j] * bvl + bj[j];
    a   = aj[j] * a;
  }
  // inclusive scan over lane composites (f_lane ∘ prefix)
  #pragma unroll
  for (int off = 1; off < 64; off <<= 1) {
    float pa  = __shfl_up(a, off);
    float pbv = __shfl_up(bvl, off);
    if (lane >= off) { bvl = a * pbv + bvl; a = a * pa; }
  }
  // state entering this lane's first chunk (x_0 = 0)
  float X = __shfl_up(bvl, 1);
  if (lane == 0) X = 0.f;
  #pragma unroll
  for (int j = 0; j < 4; j++) {
    int c = lane * 4 + j;
    hinit[((size_t)chain * NCH + c) * DS + s] = X;
    X = aj[j] * X + bj[j];
  }
}

// ---------------------------------------------------------------- scan pass C: re-run with true init, y = scan_y * silu(z)
// z lives in uz buffer at column offset DI, row stride 2*DI.  y may alias delta
// (same-thread read-before-write per element).
__global__ void scan_passC(const float* __restrict__ delta, const float* __restrict__ uc,
                           const float* __restrict__ xdbl, const float* __restrict__ A_log,
                           const float* __restrict__ Dp, const float* __restrict__ uz,
                           const float* __restrict__ hinit, float* __restrict__ y) {
  int b = blockIdx.x / NCH, c = blockIdx.x % NCH;
  int d = threadIdx.x;
  __shared__ float Bsh[CH][DS];
  __shared__ float Csh[CH][DS];
  {
    int i = threadIdx.x;   // CH*DS == 256 exactly
    int t0 = i / DS, s = i % DS;
    size_t rb = ((size_t)b * L + c * CH + t0) * XDW;
    Bsh[t0][s] = xdbl[rb + DRR + s];
    Csh[t0][s] = xdbl[rb + DRR + DS + s];
  }
  __syncthreads();
  float Av[DS];
  #pragma unroll
  for (int s = 0; s < DS; s++) Av[s] = -__expf(A_log[d * DS + s]);
  size_t chain = (size_t)b * DI + d;
  float st[DS];
  #pragma unroll
  for (int s = 0; s < DS; s++) st[s] = hinit[(chain * NCH + c) * DS + s];
  float Dv = Dp[d];
  const float* dl_p = delta + ((size_t)b * L + c * CH) * DI + d;
  const float* uc_p = uc    + ((size_t)b * L + c * CH) * DI + d;
  const float* z_p  = uz    + ((size_t)b * L + c * CH) * (2 * DI) + DI + d;
  float* y_p        = y     + ((size_t)b * L + c * CH) * DI + d;
  for (int t0 = 0; t0 < CH; t0++) {
    float dl = dl_p[(size_t)t0 * DI];
    float ut = uc_p[(size_t)t0 * DI];
    float du = dl * ut;
    float acc = Dv * ut;
    #pragma unroll
    for (int s = 0; s < DS; s++) {
      float a = __expf(dl * Av[s]);
      st[s] = a * st[s] + du * Bsh[t0][s];
      acc += st[s] * Csh[t0][s];
    }
    float zz = z_p[(size_t)t0 * (2 * DI)];
    float sz = zz / (1.f + __expf(-zz));
    y_p[(size_t)t0 * DI] = acc * sz;
  }
}

// ---------------------------------------------------------------- final mean helpers
__global__ void zero_kernel(float* __restrict__ p, int n) {
  int i = blockIdx.x * 256 + threadIdx.x;
  if (i < n) p[i] = 0.f;
}

// grid: BATCH*64 blocks x 128 threads; each block sums 64 rows of one batch
__global__ void colsum_kernel(const float* __restrict__ xn, float* __restrict__ hm) {
  int b = blockIdx.x / 64;
  int r0 = (blockIdx.x % 64) * 64;
  int e = threadIdx.x;
  float acc = 0.f;
  for (int r = 0; r < 64; r++) acc += xn[((size_t)b * L + r0 + r) * E + e];
  atomicAdd(&hm[b * E + e], acc);
}

__global__ void fc_kernel(const float* __restrict__ hm, const float* __restrict__ fcw,
                          const float* __restrict__ fcb, float* __restrict__ out) {
  int i = threadIdx.x;
  if (i >= BATCH * NC) return;
  int b = i / NC, o = i % NC;
  float acc = 0.f;
  for (int e = 0; e < E; e++) acc += hm[b * E + e] * fcw[o * E + e];
  out[i] = acc * (1.f / L) + fcb[o];
}

// ---------------------------------------------------------------- launch
extern "C" void kernel_launch(void* const* d_in, const int* in_sizes, int n_in,
                              void* d_out, int out_size, void* d_ws, size_t ws_size,
                              hipStream_t stream) {
  const float* x      = (const float*)d_in[0];
  const int*   oh     = (const int*)d_in[1];
  const int*   ot     = (const int*)d_in[2];
  const float* pe_w   = (const float*)d_in[3];
  const float* pe_b   = (const float*)d_in[4];
  const float* gamma  = (const float*)d_in[5];
  const float* beta   = (const float*)d_in[6];
  const float* ln_g   = (const float*)d_in[7];
  const float* ln_b   = (const float*)d_in[8];
  const float* inproj = (const float*)d_in[9];
  const float* conv_w = (const float*)d_in[10];
  const float* conv_b = (const float*)d_in[11];
  const float* xproj  = (const float*)d_in[12];
  const float* dtw    = (const float*)d_in[13];
  const float* dtb    = (const float*)d_in[14];
  const float* A_log  = (const float*)d_in[15];
  const float* Dp     = (const float*)d_in[16];
  const float* outw   = (const float*)d_in[17];
  const float* hn_g   = (const float*)d_in[18];
  const float* hn_b   = (const float*)d_in[19];
  const float* fc_w   = (const float*)d_in[20];
  const float* fc_b   = (const float*)d_in[21];
  float* out = (float*)d_out;

  char* ws = (char*)d_ws;
  size_t off = 0;
  auto alloc = [&](size_t bytes) { size_t o = off; off += (bytes + 255) & ~(size_t)255; return o; };
  float* h     = (float*)(ws + alloc((size_t)ROWS * E * 4));              // 8 MB
  float* xn    = (float*)(ws + alloc((size_t)ROWS * E * 4));              // 8 MB
  float* uz    = (float*)(ws + alloc((size_t)ROWS * 2 * DI * 4));         // 32 MB
  float* uc    = (float*)(ws + alloc((size_t)ROWS * DI * 4));             // 16 MB
  float* xdbl  = (float*)(ws + alloc((size_t)ROWS * XDW * 4));            // 2.6 MB
  float* delta = (float*)(ws + alloc((size_t)ROWS * DI * 4));             // 16 MB
  float* hloc  = (float*)(ws + alloc((size_t)BATCH * DI * NCH * DS * 4)); // 16.8 MB
  float* sumd  = (float*)(ws + alloc((size_t)BATCH * DI * NCH * 4));      // 1 MB
  float* hm    = (float*)(ws + alloc((size_t)BATCH * E * 4));             // 2 KB
  float* hinit = hloc;    // passB: same-thread read-before-write per element
  float* y     = delta;   // passC: same-thread read-before-write per element

  embed_kernel<<<(ROWS * E + 255) / 256, 256, 0, stream>>>(x, oh, ot, pe_w, pe_b, gamma, beta, h);

  for (int i = 0; i < NBLK; i++) {
    ln_kernel<<<ROWS / 4, 256, 0, stream>>>(h, xn, ln_g + i * E, ln_b + i * E, ROWS);

    // fused u|z projection: (ROWS, 2*DI) = xn @ inproj^T
    dim3 g1(ROWS / 64, (2 * DI) / 64);
    gemm_bt<0, 0><<<g1, 256, 0, stream>>>(xn, E, inproj + (size_t)i * 2 * DI * E, E,
                                          nullptr, uz, 2 * DI, ROWS, 2 * DI, E);

    conv_silu<<<(ROWS * DI + 255) / 256, 256, 0, stream>>>(uz, conv_w + i * DI * DCV, conv_b + i * DI, uc);

    dim3 g2(ROWS / 64, (XDW + 63) / 64);
    gemm_bt<0, 0><<<g2, 256, 0, stream>>>(uc, DI, xproj + (size_t)i * XDW * DI, DI,
                                          nullptr, xdbl, XDW, ROWS, XDW, DI);

    dim3 g3(ROWS / 64, DI / 64);
    gemm_bt<1, 0><<<g3, 256, 0, stream>>>(xdbl, XDW, dtw + (size_t)i * DI * DRR, DRR,
                                          dtb + i * DI, delta, DI, ROWS, DI, DRR);

    scan_passA<<<BATCH * NCH, 256, 0, stream>>>(delta, uc, xdbl, A_log + (size_t)i * DI * DS, hloc, sumd);
    scan_passB<<<(BATCH * DI * DS) / 4, 256, 0, stream>>>(A_log + (size_t)i * DI * DS, hloc, sumd, hinit);
    scan_passC<<<BATCH * NCH, 256, 0, stream>>>(delta, uc, xdbl, A_log + (size_t)i * DI * DS,
                                                Dp + i * DI, uz, hinit, y);

    dim3 g4(ROWS / 64, E / 64);
    gemm_bt<0, 1><<<g4, 256, 0, stream>>>(y, DI, outw + (size_t)i * E * DI, DI,
                                          nullptr, h, E, ROWS, E, DI);
  }

  ln_kernel<<<ROWS / 4, 256, 0, stream>>>(h, xn, hn_g, hn_b, ROWS);
  zero_kernel<<<2, 256, 0, stream>>>(hm, BATCH * E);
  colsum_kernel<<<BATCH * 64, 128, 0, stream>>>(xn, hm);
  fc_kernel<<<1, 192, 0, stream>>>(hm, fc_w, fc_b, out);
}